// Round 1
// baseline (10176.064 us; speedup 1.0000x reference)
//
#include <hip/hip_runtime.h>
#include <math.h>

// Problem constants (from reference): S=512, B=64, I=512, H=1024, fp32.
#define RS 512
#define RB 64
#define RI 512
#define RH 1024

// ---------------------------------------------------------------------------
// Kernel 1: Vx = x @ Vw^T + Vb
//   C[m,n] = sum_k A[m,k] * W[n,k] + bias[n]
//   M = S*B = 32768, N = H = 1024, K = I = 512
// Tile 64x64, BK=16, 256 threads (16x16), 4x4 microtile, fp32.
// ---------------------------------------------------------------------------
__global__ __launch_bounds__(256) void vx_gemm(const float* __restrict__ A,
                                               const float* __restrict__ W,
                                               const float* __restrict__ bias,
                                               float* __restrict__ C,
                                               int M, int N, int K) {
    __shared__ __align__(16) float As[16][68];  // [k][m], pad 68 to kill store conflicts, keep 16B align
    __shared__ __align__(16) float Bs[16][68];  // [k][n]

    const int tx = threadIdx.x;            // 0..15 -> n
    const int ty = threadIdx.y;            // 0..15 -> m
    const int tid = ty * 16 + tx;
    const int m0 = blockIdx.y * 64;
    const int n0 = blockIdx.x * 64;

    float acc[4][4] = {};

    const int row  = tid >> 2;             // 0..63
    const int quad = tid & 3;              // 0..3 -> k offset quad*4

    for (int k0 = 0; k0 < K; k0 += 16) {
        // Stage A tile (64 m x 16 k) and W tile (64 n x 16 k), transposed into LDS.
        float4 av = *(const float4*)&A[(size_t)(m0 + row) * K + k0 + quad * 4];
        float4 wv = *(const float4*)&W[(size_t)(n0 + row) * K + k0 + quad * 4];
        const int kq = quad * 4;
        As[kq + 0][row] = av.x; As[kq + 1][row] = av.y;
        As[kq + 2][row] = av.z; As[kq + 3][row] = av.w;
        Bs[kq + 0][row] = wv.x; Bs[kq + 1][row] = wv.y;
        Bs[kq + 2][row] = wv.z; Bs[kq + 3][row] = wv.w;
        __syncthreads();

        #pragma unroll
        for (int k = 0; k < 16; ++k) {
            float4 a = *(const float4*)&As[k][ty * 4];
            float4 b = *(const float4*)&Bs[k][tx * 4];
            float am[4] = {a.x, a.y, a.z, a.w};
            float bn[4] = {b.x, b.y, b.z, b.w};
            #pragma unroll
            for (int i = 0; i < 4; ++i)
                #pragma unroll
                for (int j = 0; j < 4; ++j)
                    acc[i][j] = fmaf(am[i], bn[j], acc[i][j]);
        }
        __syncthreads();
    }

    // Epilogue: add bias, store float4.
    #pragma unroll
    for (int i = 0; i < 4; ++i) {
        const int m = m0 + ty * 4 + i;
        const int n = n0 + tx * 4;
        float4 o;
        o.x = acc[i][0] + bias[n + 0];
        o.y = acc[i][1] + bias[n + 1];
        o.z = acc[i][2] + bias[n + 2];
        o.w = acc[i][3] + bias[n + 3];
        *(float4*)&C[(size_t)m * N + n] = o;
    }
}

// ---------------------------------------------------------------------------
// Kernel 2: one recurrence step, in place.
//   hseq_t[b,j] (holds Vx_t on entry) <- tanh( sum_k Ww[j,k]*h_prev[b,k]
//                                              + Wb[j] + Vx_t[b,j] )
// Grid: (16 j-slices of 64) x (16 b-groups of 4). Block: (64,4) = 4 waves.
// Wave = 64 j-lanes (Ww streamed from LDS, conflict-free);
// h broadcast from LDS (wave-uniform address -> free).
// ---------------------------------------------------------------------------
__global__ __launch_bounds__(256) void rnn_step(const float* __restrict__ h_prev,
                                                const float* __restrict__ Ww,
                                                const float* __restrict__ Wb,
                                                float* __restrict__ hseq_t,
                                                int has_prev) {
    __shared__ __align__(16) float Ws[64][66];  // [k][j], pad 66
    __shared__ __align__(16) float Hs[4][64];   // [b][k]

    const int lane = threadIdx.x;   // 0..63 -> j offset
    const int w    = threadIdx.y;   // 0..3  -> b offset
    const int j0 = blockIdx.x * 64;
    const int b0 = blockIdx.y * 4;
    const int j = j0 + lane;
    const int b = b0 + w;

    float acc = 0.0f;

    if (has_prev) {
        const int tid  = w * 64 + lane;
        const int row  = tid >> 2;        // 0..63  (j row of Ww slice)
        const int quad = tid & 3;         // 0..3   (k chunk of 16)

        for (int k0 = 0; k0 < RH; k0 += 64) {
            // Stage Ww[j0+row][k0 + quad*16 .. +15] -> Ws[k][row] (transposed)
            const float* src = &Ww[(size_t)(j0 + row) * RH + k0 + quad * 16];
            float4 v[4];
            v[0] = *(const float4*)(src + 0);
            v[1] = *(const float4*)(src + 4);
            v[2] = *(const float4*)(src + 8);
            v[3] = *(const float4*)(src + 12);
            #pragma unroll
            for (int r = 0; r < 4; ++r) {
                const int kq = quad * 16 + r * 4;
                Ws[kq + 0][row] = v[r].x;
                Ws[kq + 1][row] = v[r].y;
                Ws[kq + 2][row] = v[r].z;
                Ws[kq + 3][row] = v[r].w;
            }
            // Stage h_prev[b0..b0+3][k0..k0+63] -> Hs
            if (tid < 64) {
                const int hb = tid >> 4;         // 0..3
                const int hk = (tid & 15) * 4;   // 0..60
                float4 hv = *(const float4*)&h_prev[(size_t)(b0 + hb) * RH + k0 + hk];
                Hs[hb][hk + 0] = hv.x; Hs[hb][hk + 1] = hv.y;
                Hs[hb][hk + 2] = hv.z; Hs[hb][hk + 3] = hv.w;
            }
            __syncthreads();

            #pragma unroll 16
            for (int k = 0; k < 64; ++k)
                acc = fmaf(Hs[w][k], Ws[k][lane], acc);
            __syncthreads();
        }
    }

    const float vx = hseq_t[(size_t)b * RH + j];
    hseq_t[(size_t)b * RH + j] = tanhf(acc + Wb[j] + vx);
}

// ---------------------------------------------------------------------------
extern "C" void kernel_launch(void* const* d_in, const int* in_sizes, int n_in,
                              void* d_out, int out_size, void* d_ws, size_t ws_size,
                              hipStream_t stream) {
    const float* x  = (const float*)d_in[0];  // (S,B,I)
    const float* Ww = (const float*)d_in[1];  // (H,H)
    const float* Wb = (const float*)d_in[2];  // (H)
    const float* Vw = (const float*)d_in[3];  // (H,I)
    const float* Vb = (const float*)d_in[4];  // (H)

    float* out  = (float*)d_out;
    float* hseq = out;  // first S*B*H floats; h_final is the trailing B*H.

    // 1) Vx = x @ Vw^T + Vb, written into the h_seq region (consumed in place).
    {
        dim3 grid(RH / 64, (RS * RB) / 64);
        dim3 block(16, 16);
        vx_gemm<<<grid, block, 0, stream>>>(x, Vw, Vb, hseq, RS * RB, RH, RI);
    }

    // 2) 512 sequential steps, in place over the h_seq region.
    {
        dim3 grid(16, 16);   // 16 j-slices x 16 b-groups
        dim3 block(64, 4);
        for (int t = 0; t < RS; ++t) {
            const float* hp = (t == 0) ? nullptr : hseq + (size_t)(t - 1) * RB * RH;
            rnn_step<<<grid, block, 0, stream>>>(hp, Ww, Wb,
                                                 hseq + (size_t)t * RB * RH,
                                                 t == 0 ? 0 : 1);
        }
    }

    // 3) h_final = h_seq[S-1]
    hipMemcpyAsync(out + (size_t)RS * RB * RH, hseq + (size_t)(RS - 1) * RB * RH,
                   sizeof(float) * RB * RH, hipMemcpyDeviceToDevice, stream);
}

// Round 2
// 7850.504 us; speedup vs baseline: 1.2962x; 1.2962x over previous
//
#include <hip/hip_runtime.h>
#include <math.h>

// Problem constants: S=512, B=64, I=512, H=1024, fp32.
#define RS 512
#define RB 64
#define RI 512
#define RH 1024

#define NG   8    // batch groups (XCD-aligned via blockIdx&7)
#define WPG  32   // workgroups per group
#define BPG  8    // batches per group (64/8)

// ---------------------------------------------------------------------------
// Kernel 1: Vx = x @ Vw^T + Vb   (unchanged from R1 — measured-correct)
// ---------------------------------------------------------------------------
__global__ __launch_bounds__(256) void vx_gemm(const float* __restrict__ A,
                                               const float* __restrict__ W,
                                               const float* __restrict__ bias,
                                               float* __restrict__ C,
                                               int M, int N, int K) {
    __shared__ __align__(16) float As[16][68];
    __shared__ __align__(16) float Bs[16][68];

    const int tx = threadIdx.x;
    const int ty = threadIdx.y;
    const int tid = ty * 16 + tx;
    const int m0 = blockIdx.y * 64;
    const int n0 = blockIdx.x * 64;

    float acc[4][4] = {};

    const int row  = tid >> 2;
    const int quad = tid & 3;

    for (int k0 = 0; k0 < K; k0 += 16) {
        float4 av = *(const float4*)&A[(size_t)(m0 + row) * K + k0 + quad * 4];
        float4 wv = *(const float4*)&W[(size_t)(n0 + row) * K + k0 + quad * 4];
        const int kq = quad * 4;
        As[kq + 0][row] = av.x; As[kq + 1][row] = av.y;
        As[kq + 2][row] = av.z; As[kq + 3][row] = av.w;
        Bs[kq + 0][row] = wv.x; Bs[kq + 1][row] = wv.y;
        Bs[kq + 2][row] = wv.z; Bs[kq + 3][row] = wv.w;
        __syncthreads();

        #pragma unroll
        for (int k = 0; k < 16; ++k) {
            float4 a = *(const float4*)&As[k][ty * 4];
            float4 b = *(const float4*)&Bs[k][tx * 4];
            float am[4] = {a.x, a.y, a.z, a.w};
            float bn[4] = {b.x, b.y, b.z, b.w};
            #pragma unroll
            for (int i = 0; i < 4; ++i)
                #pragma unroll
                for (int j = 0; j < 4; ++j)
                    acc[i][j] = fmaf(am[i], bn[j], acc[i][j]);
        }
        __syncthreads();
    }

    #pragma unroll
    for (int i = 0; i < 4; ++i) {
        const int m = m0 + ty * 4 + i;
        const int n = n0 + tx * 4;
        float4 o;
        o.x = acc[i][0] + bias[n + 0];
        o.y = acc[i][1] + bias[n + 1];
        o.z = acc[i][2] + bias[n + 2];
        o.w = acc[i][3] + bias[n + 3];
        *(float4*)&C[(size_t)m * N + n] = o;
    }
}

// ---------------------------------------------------------------------------
// Kernel 2: persistent recurrence.
// 256 WGs x 256 thr. group g = blockIdx&7 (XCD round-robin heuristic),
// sub = blockIdx>>3. WG owns j-slice [sub*32, sub*32+32) for batches
// [g*8, g*8+8). Ww slice lives in REGISTERS (128 VGPR/thread).
// Thread roles:
//   compute: kc = wave*4 + (lane>>4) in [0,16) -> k-chunk of 64
//            jp = lane&15              -> j-pair (2 j's)
//   output : o_jl = tid&31 (j), o_bl = tid>>5 (batch)
// Per step: stage group h_{t-1} (agent-atomic u64 loads -> LDS, kc-staggered,
// conflict-free b128 broadcast reads), 64x16 FMA loop, 16-way k reduce via
// LDS, tanh epilogue in place over Vx, publish h_t (agent atomics), flag
// barrier with step-number sense.
// ---------------------------------------------------------------------------
__global__ __launch_bounds__(256, 1) void rnn_persistent(
    const float* __restrict__ Ww, const float* __restrict__ Wb,
    float* __restrict__ hseq, float* __restrict__ hfin,
    float* __restrict__ hex, int* __restrict__ flags)
{
    const int tid  = threadIdx.x;
    const int wgid = blockIdx.x;
    const int g    = wgid & 7;
    const int sub  = wgid >> 3;
    const int j0   = sub * 32;
    const int b0   = g * BPG;

    const int wave = tid >> 6, lane = tid & 63;
    const int kc = wave * 4 + (lane >> 4);   // 0..15
    const int jp = lane & 15;                // 0..15

    const int o_jl = tid & 31, o_bl = tid >> 5;
    const int oj = j0 + o_jl;

    // Preload Ww[j0+jp*2 .. +1][kc*64 .. +63] into registers.
    float wreg[2][64];
    {
        const float* base = Ww + (size_t)(j0 + jp * 2) * RH + kc * 64;
        #pragma unroll
        for (int jj = 0; jj < 2; ++jj)
            #pragma unroll
            for (int ki = 0; ki < 64; ki += 4) {
                float4 v = *(const float4*)(base + (size_t)jj * RH + ki);
                wreg[jj][ki + 0] = v.x; wreg[jj][ki + 1] = v.y;
                wreg[jj][ki + 2] = v.z; wreg[jj][ki + 3] = v.w;
            }
    }
    const float wb = Wb[oj];

    __shared__ __align__(16) float Hs[8256];   // [k][8b] with +4 float stagger per kc
    __shared__ __align__(16) float Red[4096];  // [kc][jp][2jj][8b]

    int* gflags = flags + g * WPG;

    for (int t = 0; t < RS; ++t) {
        float acc[16];
        #pragma unroll
        for (int i = 0; i < 16; ++i) acc[i] = 0.f;

        if (t > 0) {
            // Stage h_{t-1}: exchange buf [k][b] -> LDS staggered.
            const unsigned long long* src = (const unsigned long long*)
                (hex + ((size_t)((t - 1) & 1) * NG + g) * (RH * BPG));
            #pragma unroll
            for (int i = 0; i < 16; ++i) {
                const int idx = tid + 256 * i;         // float2 index
                unsigned long long u = __hip_atomic_load(src + idx,
                    __ATOMIC_RELAXED, __HIP_MEMORY_SCOPE_AGENT);
                union { unsigned long long u; float f[2]; } cv; cv.u = u;
                const int k = idx >> 2, q = idx & 3;
                const int base = k * 8 + (k >> 6) * 4 + q * 2;
                Hs[base] = cv.f[0]; Hs[base + 1] = cv.f[1];
            }
            __syncthreads();

            const float4* hv = (const float4*)Hs;
            const int hbase = kc * 129;                // (kc*516)/4
            #pragma unroll
            for (int ki = 0; ki < 64; ++ki) {
                const float4 h0 = hv[hbase + ki * 2];
                const float4 h1 = hv[hbase + ki * 2 + 1];
                const float w0 = wreg[0][ki], w1 = wreg[1][ki];
                acc[0]  = fmaf(w0, h0.x, acc[0]);  acc[1]  = fmaf(w0, h0.y, acc[1]);
                acc[2]  = fmaf(w0, h0.z, acc[2]);  acc[3]  = fmaf(w0, h0.w, acc[3]);
                acc[4]  = fmaf(w0, h1.x, acc[4]);  acc[5]  = fmaf(w0, h1.y, acc[5]);
                acc[6]  = fmaf(w0, h1.z, acc[6]);  acc[7]  = fmaf(w0, h1.w, acc[7]);
                acc[8]  = fmaf(w1, h0.x, acc[8]);  acc[9]  = fmaf(w1, h0.y, acc[9]);
                acc[10] = fmaf(w1, h0.z, acc[10]); acc[11] = fmaf(w1, h0.w, acc[11]);
                acc[12] = fmaf(w1, h1.x, acc[12]); acc[13] = fmaf(w1, h1.y, acc[13]);
                acc[14] = fmaf(w1, h1.z, acc[14]); acc[15] = fmaf(w1, h1.w, acc[15]);
            }

            // k-split partials -> LDS
            float4* rp = (float4*)&Red[(kc * 16 + jp) * 16];
            rp[0] = make_float4(acc[0],  acc[1],  acc[2],  acc[3]);
            rp[1] = make_float4(acc[4],  acc[5],  acc[6],  acc[7]);
            rp[2] = make_float4(acc[8],  acc[9],  acc[10], acc[11]);
            rp[3] = make_float4(acc[12], acc[13], acc[14], acc[15]);
            __syncthreads();
        }

        // Epilogue: 16-way reduce + bias + Vx + tanh, in place.
        float z = 0.f;
        if (t > 0) {
            const int rbase = (o_jl >> 1) * 16 + (o_jl & 1) * 8 + o_bl;
            #pragma unroll
            for (int kk = 0; kk < 16; ++kk)
                z += Red[kk * 256 + rbase];
        }
        float* cell = hseq + (size_t)t * (RB * RH) + (size_t)(b0 + o_bl) * RH + oj;
        const float h = tanhf(z + wb + *cell);
        *cell = h;

        if (t == RS - 1) {
            hfin[(size_t)(b0 + o_bl) * RH + oj] = h;
        } else {
            // Publish h_t for group consumers (coherence-point store).
            __hip_atomic_store(
                hex + ((size_t)(t & 1) * NG + g) * (RH * BPG) + (size_t)oj * BPG + o_bl,
                h, __ATOMIC_RELAXED, __HIP_MEMORY_SCOPE_AGENT);
            __syncthreads();  // compiler drains vmcnt(0) for every wave before s_barrier
            if (tid == 0)
                __hip_atomic_store(&gflags[sub], t + 1,
                                   __ATOMIC_RELEASE, __HIP_MEMORY_SCOPE_AGENT);
            if (wave == 0) {
                const int target = t + 1;
                const int idx = lane & 31;
                while (__hip_atomic_load(&gflags[idx], __ATOMIC_RELAXED,
                                         __HIP_MEMORY_SCOPE_AGENT) < target) {}
            }
            __syncthreads();
        }
    }
}

// ---------------------------------------------------------------------------
extern "C" void kernel_launch(void* const* d_in, const int* in_sizes, int n_in,
                              void* d_out, int out_size, void* d_ws, size_t ws_size,
                              hipStream_t stream) {
    const float* x  = (const float*)d_in[0];  // (S,B,I)
    const float* Ww = (const float*)d_in[1];  // (H,H)
    const float* Wb = (const float*)d_in[2];  // (H)
    const float* Vw = (const float*)d_in[3];  // (H,I)
    const float* Vb = (const float*)d_in[4];  // (H)

    float* out  = (float*)d_out;
    float* hseq = out;                                  // (S,B,H)
    float* hfin = out + (size_t)RS * RB * RH;           // (B,H)

    // Workspace: [256 int flags][pad to 1KB][2 x 8 groups x 1024 x 8 float hex]
    int*   flags = (int*)d_ws;
    float* hex   = (float*)((char*)d_ws + 1024);

    // 1) Vx = x @ Vw^T + Vb  -> hseq (consumed in place by recurrence)
    {
        dim3 grid(RH / 64, (RS * RB) / 64);
        dim3 block(16, 16);
        vx_gemm<<<grid, block, 0, stream>>>(x, Vw, Vb, hseq, RS * RB, RH, RI);
    }

    // 2) Persistent recurrence: one WG per CU, group-local flag barriers.
    rnn_persistent<<<dim3(NG * WPG), dim3(256), 0, stream>>>(Ww, Wb, hseq, hfin,
                                                             hex, flags);
}